// Round 5
// baseline (695.584 us; speedup 1.0000x reference)
//
#include <hip/hip_runtime.h>
#include <math.h>

// Problem constants (fixed by the reference)
#define BN 16384
#define DN 512
#define KN 16384
#define HN 256
#define ZN 128

typedef _Float16 f16x8 __attribute__((ext_vector_type(8)));
typedef _Float16 f16x4 __attribute__((ext_vector_type(4)));
typedef float f32x4 __attribute__((ext_vector_type(4)));

// ---------------------------------------------------------------------------
// Transpose all four weight matrices so GEMM lanes stream contiguous W-rows.
// W1[512][256]->W1t[256][512], W4[256][512]->W4t[512][256],
// W2[256][128]->W2t[128][256], W3[128][256]->W3t[256][128].
// ---------------------------------------------------------------------------
__global__ __launch_bounds__(256) void wtrans_kernel(
    const float* __restrict__ W1, const float* __restrict__ W2,
    const float* __restrict__ W3, const float* __restrict__ W4,
    float* __restrict__ W1t, float* __restrict__ W2t,
    float* __restrict__ W3t, float* __restrict__ W4t)
{
    const int g = blockIdx.x * 256 + threadIdx.x;
    if (g < 131072) {                       // W1: k=g>>8, j=g&255
        W1t[(size_t)(g & 255) * 512 + (g >> 8)] = W1[g];
    } else if (g < 262144) {                // W4: k=i>>9, d=i&511
        const int i = g - 131072;
        W4t[(size_t)(i & 511) * 256 + (i >> 9)] = W4[i];
    } else if (g < 294912) {                // W2: k=i>>7, j=i&127
        const int i = g - 262144;
        W2t[(size_t)(i & 127) * 256 + (i >> 7)] = W2[i];
    } else {                                // W3: k=i>>8, j=i&255
        const int i = g - 294912;
        W3t[(size_t)(i & 255) * 128 + (i >> 8)] = W3[i];
    }
}

// ---------------------------------------------------------------------------
// enc1: GEMM1 + LayerNorm + GELU -> hbg[B][256] (global fp32).
// j = tid (keeps LN butterfly bit-identical to the passing kernel).
// x operand: block-uniform s_load from feat; W1t rows per-lane (L1-resident).
// No LDS in the GEMM loop.
// ---------------------------------------------------------------------------
__global__ __launch_bounds__(256) void enc1_kernel(
    const float* __restrict__ feat, const float* __restrict__ W1t, const float* __restrict__ b1,
    const float* __restrict__ g1, const float* __restrict__ be1,
    float* __restrict__ hbg)
{
    __shared__ float red1[4][16];
    __shared__ float red2[4][16];
    const int tid = threadIdx.x;
    const int rbase = blockIdx.x * 16;
    const int j = tid;

    float acc[16];
    {
        float bias = b1[j];
        #pragma unroll
        for (int r = 0; r < 16; ++r) acc[r] = bias;
    }
    const float* wrow = W1t + (size_t)j * 512;
    for (int k = 0; k < 512; k += 4) {
        float4 wv = *((const float4*)(wrow + k));
        #pragma unroll
        for (int r = 0; r < 16; ++r) {
            float4 xv = *((const float4*)(feat + (size_t)(rbase + r) * 512 + k));  // uniform -> s_load
            acc[r] = fmaf(xv.x, wv.x, acc[r]);
            acc[r] = fmaf(xv.y, wv.y, acc[r]);
            acc[r] = fmaf(xv.z, wv.z, acc[r]);
            acc[r] = fmaf(xv.w, wv.w, acc[r]);
        }
    }

    // LayerNorm over H=256 (identical reduction order to prior rounds)
    float s1[16], s2[16];
    #pragma unroll
    for (int r = 0; r < 16; ++r) { s1[r] = acc[r]; s2[r] = acc[r] * acc[r]; }
    #pragma unroll
    for (int m = 1; m < 64; m <<= 1) {
        #pragma unroll
        for (int r = 0; r < 16; ++r) {
            s1[r] += __shfl_xor(s1[r], m, 64);
            s2[r] += __shfl_xor(s2[r], m, 64);
        }
    }
    const int wave = tid >> 6, lane = tid & 63;
    if (lane == 0) {
        #pragma unroll
        for (int r = 0; r < 16; ++r) { red1[wave][r] = s1[r]; red2[wave][r] = s2[r]; }
    }
    __syncthreads();
    {
        float gg = g1[j], bb = be1[j];
        #pragma unroll
        for (int r = 0; r < 16; ++r) {
            float sum = red1[0][r] + red1[1][r] + red1[2][r] + red1[3][r];
            float ssq = red2[0][r] + red2[1][r] + red2[2][r] + red2[3][r];
            float mu = sum * (1.0f / 256.0f);
            float var = fmaxf(ssq * (1.0f / 256.0f) - mu * mu, 0.0f);
            float rstd = rsqrtf(var + 1e-5f);
            float t = (acc[r] - mu) * rstd * gg + bb;
            hbg[(size_t)(rbase + r) * 256 + j] = 0.5f * t * (1.0f + erff(t * 0.70710678118654752f));
        }
    }
}

// ---------------------------------------------------------------------------
// enc2: GEMM2 -> encoded[B][128] + f16 hi/lo split.
// x operand: wave-uniform s_load from hbg; W2t rows per-lane.
// Chain order identical to prior rounds (k ascending, x.x..x.w).
// ---------------------------------------------------------------------------
__global__ __launch_bounds__(256) void enc2_kernel(
    const float* __restrict__ hbg, const float* __restrict__ W2t, const float* __restrict__ b2,
    float* __restrict__ encoded, _Float16* __restrict__ xh, _Float16* __restrict__ xl)
{
    const int tid = threadIdx.x;
    const int rbase = blockIdx.x * 16;
    const int j2 = tid & 127;
    const int rhu = __builtin_amdgcn_readfirstlane(tid >> 7);  // wave-uniform row half

    float a2[8];
    {
        float bias2 = b2[j2];
        #pragma unroll
        for (int r = 0; r < 8; ++r) a2[r] = bias2;
    }
    const float* wrow = W2t + (size_t)j2 * 256;
    for (int k = 0; k < 256; k += 4) {
        float4 wv = *((const float4*)(wrow + k));
        #pragma unroll
        for (int r = 0; r < 8; ++r) {
            float4 hv = *((const float4*)(hbg + (size_t)(rbase + rhu * 8 + r) * 256 + k));  // s_load
            a2[r] = fmaf(hv.x, wv.x, a2[r]);
            a2[r] = fmaf(hv.y, wv.y, a2[r]);
            a2[r] = fmaf(hv.z, wv.z, a2[r]);
            a2[r] = fmaf(hv.w, wv.w, a2[r]);
        }
    }
    #pragma unroll
    for (int r = 0; r < 8; ++r) {
        const size_t idx = (size_t)(rbase + rhu * 8 + r) * 128 + j2;
        const float v = a2[r];
        encoded[idx] = v;
        _Float16 hh = (_Float16)v;
        xh[idx] = hh;
        xl[idx] = (_Float16)(v - (float)hh);
    }
}

// ---------------------------------------------------------------------------
// Split+pack codebook into MFMA-fragment-linear blobs AND compute cnorm.
// Blob layout per ctile c (64 cols): 32KB = [hi/lo][ct(4)][q(16)][lr(16)][8].
// ---------------------------------------------------------------------------
__global__ __launch_bounds__(256) void split_kernel(
    const float* __restrict__ cb, _Float16* __restrict__ cpk, float* __restrict__ cnorm)
{
    const int t = threadIdx.x;
    const int col = blockIdx.x * 8 + (t >> 5);
    const int k0 = (t & 31) * 4;
    float4 v = *(const float4*)(cb + (size_t)col * 128 + k0);
    f16x4 h, l;
    h.x = (_Float16)v.x; l.x = (_Float16)(v.x - (float)h.x);
    h.y = (_Float16)v.y; l.y = (_Float16)(v.y - (float)h.y);
    h.z = (_Float16)v.z; l.z = (_Float16)(v.z - (float)h.z);
    h.w = (_Float16)v.w; l.w = (_Float16)(v.w - (float)h.w);
    const size_t base = (size_t)(col >> 6) * 16384 + (size_t)((col >> 4) & 3) * 2048
                      + (size_t)(k0 >> 3) * 128 + (size_t)(col & 15) * 8 + (k0 & 7);
    *(f16x4*)(cpk + base) = h;
    *(f16x4*)(cpk + base + 8192) = l;

    float s = v.x * v.x + v.y * v.y + v.z * v.z + v.w * v.w;
    #pragma unroll
    for (int m = 1; m < 32; m <<= 1) s += __shfl_xor(s, m, 64);
    if ((t & 31) == 0) cnorm[col] = s;
}

// ---------------------------------------------------------------------------
// Pass A: MFMA distance group-minima. xt=4: wave = 64 rows, block = 256 rows.
// Grid = 64 row-blocks x 8 K-eighths = 512 = 2 blocks/CU. Per step the same
// 32 ds_read_b128 now feed 192 MFMAs (vs 96 at xt=2) -> DS pressure halved.
// D-layout (verified r4): x-row = lane&15 (lr), c-col = (lane>>4)*4+reg.
// B blobs (32KB) double-buffered via linear global_load_lds, counted
// vmcnt(8). Output: g_ws[row][ctile] fp32.
// ---------------------------------------------------------------------------
__global__ __launch_bounds__(256, 2) void mfma_dist_kernel(
    const _Float16* __restrict__ xh, const _Float16* __restrict__ xl,
    const _Float16* __restrict__ cpk, const float* __restrict__ cnorm,
    float* __restrict__ g_ws)
{
    __shared__ __align__(16) _Float16 bs[2][16384];   // 2 x 32KB
    const int tid = threadIdx.x;
    const int w = tid >> 6, l = tid & 63;
    const int lr = l & 15, lg = l >> 4;
    const int q8 = blockIdx.x & 7;          // K-eighth (32 ctiles)
    const int rb = blockIdx.x >> 3;         // 64 row-blocks
    const int rbase = rb * 256 + w * 64;    // this wave's 64 rows
    const int ctbase = q8 * 32;

    // x fragments (B-operand) in registers: [xt][ks], hi+lo (128 VGPRs)
    f16x8 xH[4][4], xL[4][4];
    #pragma unroll
    for (int xt = 0; xt < 4; ++xt) {
        const size_t rowoff = (size_t)(rbase + xt * 16 + lr) * 128;
        #pragma unroll
        for (int ks = 0; ks < 4; ++ks) {
            xH[xt][ks] = *(const f16x8*)(xh + rowoff + ks * 32 + lg * 8);
            xL[xt][ks] = *(const f16x8*)(xl + rowoff + ks * 32 + lg * 8);
        }
    }

    // linear async staging: wave w copies its 8KB of the 32KB blob
    const char* cpkb = (const char*)cpk;
    char* lds0 = (char*)&bs[0][0];
    auto stage = [&](int buf, int ct) {
        const char* src = cpkb + ((size_t)(ctbase + ct) << 15) + (w << 13) + l * 16;
        char* dst = lds0 + (buf << 15) + (w << 13);
        #pragma unroll
        for (int i = 0; i < 8; ++i) {
            __builtin_amdgcn_global_load_lds(
                (const __attribute__((address_space(1))) unsigned int*)(src + i * 1024),
                (__attribute__((address_space(3))) unsigned int*)(dst + i * 1024),
                16, 0, 0);
        }
    };

    stage(0, 0);

    int cur = 0;
    for (int t = 0; t < 32; ++t) {
        if (t < 31) {
            stage(cur ^ 1, t + 1);
            asm volatile("s_waitcnt vmcnt(8)" ::: "memory");  // drain cur, keep next in flight
        } else {
            asm volatile("s_waitcnt vmcnt(0)" ::: "memory");
        }
        __builtin_amdgcn_s_barrier();
        asm volatile("" ::: "memory");

        const _Float16* bb = &bs[cur][0];
        f32x4 acc[4][4];   // [ct][xt]
        #pragma unroll
        for (int ct = 0; ct < 4; ++ct)
            #pragma unroll
            for (int xt = 0; xt < 4; ++xt) {
                f32x4 z = {0.0f, 0.0f, 0.0f, 0.0f};
                acc[ct][xt] = z;
            }

        __builtin_amdgcn_s_setprio(1);
        #pragma unroll
        for (int ks = 0; ks < 4; ++ks) {
            f16x8 cH[4], cL[4];
            #pragma unroll
            for (int ct = 0; ct < 4; ++ct) {
                const int off = ct * 2048 + (ks * 4 + lg) * 128 + lr * 8;
                cH[ct] = *(const f16x8*)(bb + off);
                cL[ct] = *(const f16x8*)(bb + 8192 + off);
            }
            #pragma unroll
            for (int ct = 0; ct < 4; ++ct)
                #pragma unroll
                for (int xt = 0; xt < 4; ++xt) {
                    acc[ct][xt] = __builtin_amdgcn_mfma_f32_16x16x32_f16(cH[ct], xH[xt][ks], acc[ct][xt], 0, 0, 0);
                    acc[ct][xt] = __builtin_amdgcn_mfma_f32_16x16x32_f16(cH[ct], xL[xt][ks], acc[ct][xt], 0, 0, 0);
                    acc[ct][xt] = __builtin_amdgcn_mfma_f32_16x16x32_f16(cL[ct], xH[xt][ks], acc[ct][xt], 0, 0, 0);
                }
        }
        __builtin_amdgcn_s_setprio(0);

        // epilogue: register-tree min over c (4 ct x 4 reg) + 2 shfl over lg
        const int ct = ctbase + t;
        float4 cn[4];
        #pragma unroll
        for (int c4 = 0; c4 < 4; ++c4)
            cn[c4] = *(const float4*)(cnorm + ct * 64 + c4 * 16 + lg * 4);
        #pragma unroll
        for (int xt = 0; xt < 4; ++xt) {
            float m = 3.4e38f;
            #pragma unroll
            for (int c4 = 0; c4 < 4; ++c4) {
                float v0 = fminf(fmaf(-2.0f, acc[c4][xt][0], cn[c4].x),
                                 fmaf(-2.0f, acc[c4][xt][1], cn[c4].y));
                float v1 = fminf(fmaf(-2.0f, acc[c4][xt][2], cn[c4].z),
                                 fmaf(-2.0f, acc[c4][xt][3], cn[c4].w));
                m = fminf(m, fminf(v0, v1));
            }
            m = fminf(m, __shfl_xor(m, 16, 64));
            m = fminf(m, __shfl_xor(m, 32, 64));
            if (lg == 0)
                g_ws[(size_t)(rbase + xt * 16 + lr) * 256 + ct] = m;
        }
        asm volatile("" ::: "memory");
        __builtin_amdgcn_s_barrier();
        cur ^= 1;
    }
}

// ---------------------------------------------------------------------------
// Pass B: exact fp32 refine, ballot-parallel. thr = min(g)+EPS captures the
// exact argmin and all exact ties (EPS >= 2x approx error). Lexicographic
// (value, index) merges give exact first-index tie-break.
// ---------------------------------------------------------------------------
#define REFINE_EPS 0.05f
__global__ __launch_bounds__(256) void refine_kernel(
    const float* __restrict__ encoded, const float* __restrict__ cb,
    const float* __restrict__ cnorm, const float* __restrict__ g_ws,
    int* __restrict__ idx_ws)
{
    __shared__ float xsm[128];
    __shared__ float mpart[4];
    __shared__ unsigned long long masks[4];
    __shared__ float redv[256];
    __shared__ int redi[256];
    const int row = blockIdx.x;
    const int t = threadIdx.x;
    const int w = t >> 6, lane = t & 63;

    const float g = g_ws[(size_t)row * 256 + t];
    if (t < 128) xsm[t] = encoded[(size_t)row * 128 + t];

    float m = g;
    #pragma unroll
    for (int mk = 1; mk < 64; mk <<= 1) m = fminf(m, __shfl_xor(m, mk, 64));
    if (lane == 0) mpart[w] = m;
    __syncthreads();
    const float thr = fminf(fminf(mpart[0], mpart[1]), fminf(mpart[2], mpart[3])) + REFINE_EPS;

    const unsigned long long bal = __ballot(g <= thr);
    if (lane == 0) masks[w] = bal;
    __syncthreads();

    const int col = t >> 2;     // 0..63: codebook col within group
    const int kp = t & 3;       // k-part: k in [kp*32, kp*32+32)
    float bv = 3.4e38f; int bi = 0;

    for (int wq = 0; wq < 4; ++wq) {
        unsigned long long mm = masks[wq];
        while (mm) {
            const int bit = __ffsll((unsigned long long)mm) - 1;
            mm &= mm - 1;
            const int gcol = (wq * 64 + bit) * 64 + col;
            const float4* cp = (const float4*)(cb + (size_t)gcol * 128 + kp * 32);
            const float4* xp = (const float4*)(xsm + kp * 32);
            float acc = 0.0f;
            #pragma unroll
            for (int i = 0; i < 8; ++i) {
                float4 c4 = cp[i];
                float4 x4 = xp[i];
                acc = fmaf(x4.x, c4.x, acc);
                acc = fmaf(x4.y, c4.y, acc);
                acc = fmaf(x4.z, c4.z, acc);
                acc = fmaf(x4.w, c4.w, acc);
            }
            acc += __shfl_xor(acc, 1, 64);
            acc += __shfl_xor(acc, 2, 64);
            if (kp == 0) {
                const float v = fmaf(-2.0f, acc, cnorm[gcol]);
                if (v < bv || (v == bv && gcol < bi)) { bv = v; bi = gcol; }
            }
        }
    }
    redv[t] = bv; redi[t] = bi;
    __syncthreads();
    if (t < 64) {
        #pragma unroll
        for (int s = 1; s < 4; ++s) {
            float v = redv[t + s * 64]; int ii = redi[t + s * 64];
            if (v < bv || (v == bv && ii < bi)) { bv = v; bi = ii; }
        }
        #pragma unroll
        for (int mk = 1; mk < 64; mk <<= 1) {
            float ov = __shfl_xor(bv, mk, 64);
            int oi = __shfl_xor(bi, mk, 64);
            if (ov < bv || (ov == bv && oi < bi)) { bv = ov; bi = oi; }
        }
        if (t == 0) idx_ws[row] = min(max(bi, 0), KN - 1);
    }
}

// ---------------------------------------------------------------------------
// dec1: GEMM3 + LayerNorm + GELU -> dhg[B][256].
// x operand: codebook rows via scalar loads (idx forced uniform via
// readfirstlane). j = tid keeps LN butterfly bit-identical.
// ---------------------------------------------------------------------------
__global__ __launch_bounds__(256) void dec1_kernel(
    const float* __restrict__ cb, const int* __restrict__ idx_ws,
    const float* __restrict__ W3t, const float* __restrict__ b3,
    const float* __restrict__ g2, const float* __restrict__ be2,
    float* __restrict__ dhg)
{
    __shared__ float red1[4][16];
    __shared__ float red2[4][16];
    __shared__ int idxs[16];
    const int tid = threadIdx.x;
    const int rbase = blockIdx.x * 16;
    const int j = tid;

    if (tid < 16) idxs[tid] = idx_ws[rbase + tid];   // already clamped by refine
    __syncthreads();
    int idxu[16];
    #pragma unroll
    for (int r = 0; r < 16; ++r) idxu[r] = __builtin_amdgcn_readfirstlane(idxs[r]);

    float acc[16];
    {
        float bias = b3[j];
        #pragma unroll
        for (int r = 0; r < 16; ++r) acc[r] = bias;
    }
    const float* wrow = W3t + (size_t)j * 128;
    for (int k = 0; k < 128; k += 4) {
        float4 wv = *((const float4*)(wrow + k));
        #pragma unroll
        for (int r = 0; r < 16; ++r) {
            float4 qv = *((const float4*)(cb + (size_t)idxu[r] * 128 + k));  // uniform -> s_load
            acc[r] = fmaf(qv.x, wv.x, acc[r]);
            acc[r] = fmaf(qv.y, wv.y, acc[r]);
            acc[r] = fmaf(qv.z, wv.z, acc[r]);
            acc[r] = fmaf(qv.w, wv.w, acc[r]);
        }
    }

    float s1[16], s2[16];
    #pragma unroll
    for (int r = 0; r < 16; ++r) { s1[r] = acc[r]; s2[r] = acc[r] * acc[r]; }
    #pragma unroll
    for (int m = 1; m < 64; m <<= 1) {
        #pragma unroll
        for (int r = 0; r < 16; ++r) {
            s1[r] += __shfl_xor(s1[r], m, 64);
            s2[r] += __shfl_xor(s2[r], m, 64);
        }
    }
    const int wave = tid >> 6, lane = tid & 63;
    if (lane == 0) {
        #pragma unroll
        for (int r = 0; r < 16; ++r) { red1[wave][r] = s1[r]; red2[wave][r] = s2[r]; }
    }
    __syncthreads();
    {
        float gg = g2[j], bb = be2[j];
        #pragma unroll
        for (int r = 0; r < 16; ++r) {
            float sum = red1[0][r] + red1[1][r] + red1[2][r] + red1[3][r];
            float ssq = red2[0][r] + red2[1][r] + red2[2][r] + red2[3][r];
            float mu = sum * (1.0f / 256.0f);
            float var = fmaxf(ssq * (1.0f / 256.0f) - mu * mu, 0.0f);
            float rstd = rsqrtf(var + 1e-5f);
            float t = (acc[r] - mu) * rstd * gg + bb;
            dhg[(size_t)(rbase + r) * 256 + j] = 0.5f * t * (1.0f + erff(t * 0.70710678118654752f));
        }
    }
}

// ---------------------------------------------------------------------------
// dec2: GEMM4 + per-row reconstruction MSE + global sum.
// x operand: block-uniform s_load from dhg; W4t rows (d and d+256) per-lane.
// MSE reduction order identical to prior rounds.
// ---------------------------------------------------------------------------
__global__ __launch_bounds__(256) void dec2_kernel(
    const float* __restrict__ feat, const float* __restrict__ dhg,
    const float* __restrict__ W4t, const float* __restrict__ b4,
    float* __restrict__ re_ws, float* __restrict__ sum_ws)
{
    __shared__ float red1[4][16];
    const int tid = threadIdx.x;
    const int rbase = blockIdx.x * 16;

    float a0[16], a1[16];
    {
        float bias0 = b4[tid], bias1 = b4[tid + 256];
        #pragma unroll
        for (int r = 0; r < 16; ++r) { a0[r] = bias0; a1[r] = bias1; }
    }
    const float* w0row = W4t + (size_t)tid * 256;
    const float* w1row = W4t + (size_t)(tid + 256) * 256;
    for (int k = 0; k < 256; k += 4) {
        float4 wv0 = *((const float4*)(w0row + k));
        float4 wv1 = *((const float4*)(w1row + k));
        #pragma unroll
        for (int r = 0; r < 16; ++r) {
            float4 hv = *((const float4*)(dhg + (size_t)(rbase + r) * 256 + k));  // s_load
            a0[r] = fmaf(hv.x, wv0.x, a0[r]); a1[r] = fmaf(hv.x, wv1.x, a1[r]);
            a0[r] = fmaf(hv.y, wv0.y, a0[r]); a1[r] = fmaf(hv.y, wv1.y, a1[r]);
            a0[r] = fmaf(hv.z, wv0.z, a0[r]); a1[r] = fmaf(hv.z, wv1.z, a1[r]);
            a0[r] = fmaf(hv.w, wv0.w, a0[r]); a1[r] = fmaf(hv.w, wv1.w, a1[r]);
        }
    }
    float e[16];
    #pragma unroll
    for (int r = 0; r < 16; ++r) {
        float f0 = feat[(size_t)(rbase + r) * 512 + tid];
        float f1 = feat[(size_t)(rbase + r) * 512 + tid + 256];
        float d0 = a0[r] - f0, d1 = a1[r] - f1;
        e[r] = d0 * d0 + d1 * d1;
    }
    #pragma unroll
    for (int m = 1; m < 64; m <<= 1) {
        #pragma unroll
        for (int r = 0; r < 16; ++r) e[r] += __shfl_xor(e[r], m, 64);
    }
    const int wave = tid >> 6, lane = tid & 63;
    if (lane == 0) {
        #pragma unroll
        for (int r = 0; r < 16; ++r) red1[wave][r] = e[r];
    }
    __syncthreads();
    if (tid < 16) {
        float s = (red1[0][tid] + red1[1][tid] + red1[2][tid] + red1[3][tid]) * (1.0f / 512.0f);
        re_ws[rbase + tid] = s;
        atomicAdd(sum_ws, s);
    }
}

// ---------------------------------------------------------------------------
// Finalize: scale = mean(re)+1e-8; MDL bits; write all 4 fp32 outputs.
// ---------------------------------------------------------------------------
__global__ __launch_bounds__(256) void fin_kernel(
    const float* __restrict__ re_ws, const float* __restrict__ sum_ws,
    const int* __restrict__ idx_ws, float* __restrict__ out)
{
    const int i = blockIdx.x * 256 + threadIdx.x;
    const float scale = (*sum_ws) * (1.0f / 16384.0f) + 1e-8f;
    const float re = re_ws[i];
    const float lp = -fabsf(re) / scale - logf(2.0f * scale);
    const float eb = -lp * 1.4426950408889634f;   // -log_prob / ln(2)
    const float tb = 14.0f + eb;                  // log2(K)=14
    const float ratio = 16384.0f / tb;            // D*32 = 16384
    out[i]             = re;
    out[16384 + i]     = ratio;
    out[2 * 16384 + i] = tb;
    out[3 * 16384 + i] = (float)idx_ws[i];
}

// ---------------------------------------------------------------------------
extern "C" void kernel_launch(void* const* d_in, const int* in_sizes, int n_in,
                              void* d_out, int out_size, void* d_ws, size_t ws_size,
                              hipStream_t stream)
{
    const float* feat = (const float*)d_in[0];
    const float* W1   = (const float*)d_in[1];
    const float* b1   = (const float*)d_in[2];
    const float* g1   = (const float*)d_in[3];
    const float* be1  = (const float*)d_in[4];
    const float* W2   = (const float*)d_in[5];
    const float* b2   = (const float*)d_in[6];
    const float* cb   = (const float*)d_in[7];
    const float* W3   = (const float*)d_in[8];
    const float* b3   = (const float*)d_in[9];
    const float* g2   = (const float*)d_in[10];
    const float* be2  = (const float*)d_in[11];
    const float* W4   = (const float*)d_in[12];
    const float* b4   = (const float*)d_in[13];

    char* ws = (char*)d_ws;
    const size_t MB = 1u << 20;
    float*    encoded = (float*)ws;                            // 8 MB
    _Float16* xh      = (_Float16*)(ws + 8 * MB);              // 4 MB
    _Float16* xl      = (_Float16*)(ws + 12 * MB);             // 4 MB
    _Float16* cpk     = (_Float16*)(ws + 16 * MB);             // 8 MB
    float*    big     = (float*)(ws + 24 * MB);                // 16 MB: hbg -> g_ws -> dhg
    float*    W1t     = (float*)(ws + 40 * MB);                // 512 KB
    float*    W2t     = (float*)(ws + 40 * MB + (512u << 10)); // 128 KB
    float*    W3t     = (float*)(ws + 40 * MB + (640u << 10)); // 128 KB
    float*    W4t     = (float*)(ws + 40 * MB + (768u << 10)); // 512 KB
    float*    cnorm   = (float*)(ws + 41 * MB + (256u << 10)); // 64 KB
    float*    re_ws   = (float*)(ws + 41 * MB + (320u << 10)); // 64 KB
    int*      idx_ws  = (int*)(ws + 41 * MB + (384u << 10));   // 64 KB
    float*    sum_ws  = (float*)(ws + 41 * MB + (448u << 10)); // 4 B

    float* hbg  = big;   // live: enc1 -> enc2
    float* g_ws = big;   // live: dist -> refine
    float* dhg  = big;   // live: dec1 -> dec2

    hipMemsetAsync(sum_ws, 0, sizeof(float), stream);

    hipLaunchKernelGGL(wtrans_kernel, dim3(1280), dim3(256), 0, stream,
                       W1, W2, W3, W4, W1t, W2t, W3t, W4t);
    hipLaunchKernelGGL(split_kernel, dim3(KN / 8), dim3(256), 0, stream, cb, cpk, cnorm);
    hipLaunchKernelGGL(enc1_kernel, dim3(BN / 16), dim3(256), 0, stream,
                       feat, W1t, b1, g1, be1, hbg);
    hipLaunchKernelGGL(enc2_kernel, dim3(BN / 16), dim3(256), 0, stream,
                       hbg, W2t, b2, encoded, xh, xl);
    hipLaunchKernelGGL(mfma_dist_kernel, dim3(512), dim3(256), 0, stream,
                       xh, xl, cpk, cnorm, g_ws);
    hipLaunchKernelGGL(refine_kernel, dim3(BN), dim3(256), 0, stream,
                       encoded, cb, cnorm, g_ws, idx_ws);
    hipLaunchKernelGGL(dec1_kernel, dim3(BN / 16), dim3(256), 0, stream,
                       cb, idx_ws, W3t, b3, g2, be2, dhg);
    hipLaunchKernelGGL(dec2_kernel, dim3(BN / 16), dim3(256), 0, stream,
                       feat, dhg, W4t, b4, re_ws, sum_ws);
    hipLaunchKernelGGL(fin_kernel,  dim3(BN / 256), dim3(256), 0, stream,
                       re_ws, sum_ws, idx_ws, (float*)d_out);
}